// Round 8
// baseline (174.817 us; speedup 1.0000x reference)
//
#include <hip/hip_runtime.h>
#include <math.h>

// R8 = DIAGNOSTIC PROBE. k1 never appears in rocprof top-5 (harness 1GB fills
// dominate at ~150us), so we've been blind. Each block now makes 4 passes over
// DISTINCT chunks (last pass = its real chunk, committed; passes 0-2 kept live
// via asm volatile, results discarded). k1 duration ~4x (~200us) -> surfaces
// in top-5 WITH counters. Output identical to R7. Next round reverts to the
// R7 structure + whatever fix the counters indicate.

#define WAVES_PER_BLOCK 4
#define BLOCK 256
#define D 256
#define RBATCH 4

__global__ __launch_bounds__(BLOCK) void attn_partial(
    const float* __restrict__ enc,   // [B,T,D]
    const float* __restrict__ dec,   // [B,D]
    float* __restrict__ ws,
    int T, int P, int nblk_total)
{
    const int blk   = blockIdx.x;
    const int b     = blk / P;
    const int chunk = blk % P;
    const int tid   = threadIdx.x;
    const int wave  = tid >> 6;
    const int lane  = tid & 63;

    const int rows_per_block = T / P;
    const int steps = rows_per_block / (WAVES_PER_BLOCK * RBATCH);

    const float* __restrict__ encb = enc + (size_t)b * T * D;
    const float4 dq = *reinterpret_cast<const float4*>(dec + b * D + lane * 4);

    const int nreps  = (P >= 4) ? 4 : 1;
    const int cstride = P / nreps;

    float  m = -INFINITY;
    float  l = 0.0f;
    float4 acc = {0.0f, 0.0f, 0.0f, 0.0f};

    for (int rep = 0; rep < nreps; ++rep) {
        // pass reads chunk c; final pass (rep==nreps-1) has c == chunk
        const int c = (chunk + (rep + 1) * cstride) % P;

        m = -INFINITY; l = 0.0f;
        acc.x = 0.0f; acc.y = 0.0f; acc.z = 0.0f; acc.w = 0.0f;

        const float* wbase = encb
            + (size_t)(c * rows_per_block + wave * RBATCH) * D + lane * 4;

        #pragma unroll 2
        for (int s = 0; s < steps; ++s) {
            const float* base = wbase + (size_t)s * (WAVES_PER_BLOCK * RBATCH) * D;
            const float4 x0 = *reinterpret_cast<const float4*>(base);
            const float4 x1 = *reinterpret_cast<const float4*>(base + D);
            const float4 x2 = *reinterpret_cast<const float4*>(base + 2 * D);
            const float4 x3 = *reinterpret_cast<const float4*>(base + 3 * D);

            float p0 = dq.x * x0.x + dq.y * x0.y + dq.z * x0.z + dq.w * x0.w;
            float p1 = dq.x * x1.x + dq.y * x1.y + dq.z * x1.z + dq.w * x1.w;
            float p2 = dq.x * x2.x + dq.y * x2.y + dq.z * x2.z + dq.w * x2.w;
            float p3 = dq.x * x3.x + dq.y * x3.y + dq.z * x3.z + dq.w * x3.w;

            #pragma unroll
            for (int off = 32; off >= 1; off >>= 1) {
                p0 += __shfl_xor(p0, off, 64);
                p1 += __shfl_xor(p1, off, 64);
                p2 += __shfl_xor(p2, off, 64);
                p3 += __shfl_xor(p3, off, 64);
            }

            const float mn    = fmaxf(fmaxf(fmaxf(p0, p1), fmaxf(p2, p3)), m);
            const float scale = __expf(m - mn);   // 0 when m == -inf
            const float w0 = __expf(p0 - mn);
            const float w1 = __expf(p1 - mn);
            const float w2 = __expf(p2 - mn);
            const float w3 = __expf(p3 - mn);

            acc.x = fmaf(w3, x3.x, fmaf(w2, x2.x, fmaf(w1, x1.x, fmaf(w0, x0.x, acc.x * scale))));
            acc.y = fmaf(w3, x3.y, fmaf(w2, x2.y, fmaf(w1, x1.y, fmaf(w0, x0.y, acc.y * scale))));
            acc.z = fmaf(w3, x3.z, fmaf(w2, x2.z, fmaf(w1, x1.z, fmaf(w0, x0.z, acc.z * scale))));
            acc.w = fmaf(w3, x3.w, fmaf(w2, x2.w, fmaf(w1, x1.w, fmaf(w0, x0.w, acc.w * scale))));
            l = fmaf(l, scale, w0 + w1 + w2 + w3);
            m = mn;
        }

        if (rep != nreps - 1) {
            // keep the discarded pass's results live (prevent DCE of the pass)
            asm volatile("" :: "v"(acc.x), "v"(acc.y), "v"(acc.z), "v"(acc.w),
                              "v"(m), "v"(l));
        }
    }

    // combine the 4 waves' partials in LDS -> one partial per block
    __shared__ float s_acc[WAVES_PER_BLOCK][D];
    __shared__ float s_m[WAVES_PER_BLOCK];
    __shared__ float s_l[WAVES_PER_BLOCK];

    *reinterpret_cast<float4*>(&s_acc[wave][lane * 4]) = acc;
    if (lane == 0) { s_m[wave] = m; s_l[wave] = l; }
    __syncthreads();

    if (wave == 0) {
        const float M = fmaxf(fmaxf(s_m[0], s_m[1]), fmaxf(s_m[2], s_m[3]));
        float4 a = {0.0f, 0.0f, 0.0f, 0.0f};
        float  L = 0.0f;
        #pragma unroll
        for (int wv = 0; wv < WAVES_PER_BLOCK; ++wv) {
            const float e = __expf(s_m[wv] - M);
            const float4 aw = *reinterpret_cast<const float4*>(&s_acc[wv][lane * 4]);
            a.x += e * aw.x; a.y += e * aw.y; a.z += e * aw.z; a.w += e * aw.w;
            L += e * s_l[wv];
        }
        *reinterpret_cast<float4*>(ws + (size_t)blk * D + lane * 4) = a;
        if (lane == 0) {
            float* ml = ws + (size_t)nblk_total * D;
            ml[blk * 2 + 0] = M;
            ml[blk * 2 + 1] = L;
        }
    }
}

// Kernel 2: combine P partials per batch, normalize, write out.
__global__ __launch_bounds__(BLOCK) void attn_combine(
    const float* __restrict__ ws,
    float* __restrict__ out,
    int P, int nblk_total)
{
    const int b     = blockIdx.x >> 2;
    const int cq    = blockIdx.x & 3;
    const int tid   = threadIdx.x;
    const int lane  = tid & 63;
    const int slice = tid >> 6;
    const int col   = cq * 64 + lane;

    const float* __restrict__ ml = ws + (size_t)nblk_total * D;

    float M = -INFINITY;
    for (int i = 0; i < P; ++i)
        M = fmaxf(M, ml[(b * P + i) * 2 + 0]);

    float a = 0.0f, L = 0.0f;
    for (int i = slice; i < P; i += 4) {
        const int pblk = b * P + i;
        const float e  = __expf(ml[pblk * 2 + 0] - M);
        a = fmaf(e, ws[(size_t)pblk * D + col], a);
        L = fmaf(e, ml[pblk * 2 + 1], L);
    }

    __shared__ float s_a[4][64];
    __shared__ float s_L[4];
    s_a[slice][lane] = a;
    if (lane == 0) s_L[slice] = L;
    __syncthreads();

    if (slice == 0) {
        const float at = s_a[0][lane] + s_a[1][lane] + s_a[2][lane] + s_a[3][lane];
        const float Lt = s_L[0] + s_L[1] + s_L[2] + s_L[3];
        out[b * D + col] = at / Lt;
    }
}

extern "C" void kernel_launch(void* const* d_in, const int* in_sizes, int n_in,
                              void* d_out, int out_size, void* d_ws, size_t ws_size,
                              hipStream_t stream) {
    const float* enc = (const float*)d_in[0];
    const float* dec = (const float*)d_in[1];
    float* out = (float*)d_out;
    float* ws  = (float*)d_ws;

    const int B = in_sizes[1] / D;              // dec is [B, D]
    const int T = in_sizes[0] / in_sizes[1];    // enc is [B, T, D]

    int P = 64;
    while (P > 1 && ((size_t)B * P * (D + 2) * sizeof(float)) > ws_size) P >>= 1;
    while (P > 1 && (T % (P * WAVES_PER_BLOCK * RBATCH) != 0)) P >>= 1;

    const int nblk = B * P;
    attn_partial<<<nblk, BLOCK, 0, stream>>>(enc, dec, ws, T, P, nblk);
    attn_combine<<<B * 4, BLOCK, 0, stream>>>(ws, out, P, nblk);
}

// Round 9
// 58.925 us; speedup vs baseline: 2.9668x; 2.9668x over previous
//
#include <hip/hip_runtime.h>
#include <math.h>

// Luong attention, fused single pass over enc (read exactly once).
// R9 = R7 + explicit 1-step register prefetch. R8's probe showed k1 is
// latency-bound, not BW/ALU-bound: VGPR=36 proves the compiler kept only ONE
// step's loads in flight -> every wave idles its memory pipe during the
// ~300cy butterfly+exp+accum chain. Ping-pong x-buffers (~54 VGPR, still
// under the 64-VGPR occupancy cliff) keep next step's 4 KB outstanding
// across the compute phase.

#define WAVES_PER_BLOCK 4
#define BLOCK 256
#define D 256
#define RBATCH 4

#define LOADX(v0, v1, v2, v3, ptr)                                  \
    v0 = *reinterpret_cast<const float4*>(ptr);                     \
    v1 = *reinterpret_cast<const float4*>((ptr) + D);               \
    v2 = *reinterpret_cast<const float4*>((ptr) + 2 * D);           \
    v3 = *reinterpret_cast<const float4*>((ptr) + 3 * D);

#define COMPUTE(x0, x1, x2, x3) do {                                          \
    float p0 = dq.x * x0.x + dq.y * x0.y + dq.z * x0.z + dq.w * x0.w;         \
    float p1 = dq.x * x1.x + dq.y * x1.y + dq.z * x1.z + dq.w * x1.w;         \
    float p2 = dq.x * x2.x + dq.y * x2.y + dq.z * x2.z + dq.w * x2.w;         \
    float p3 = dq.x * x3.x + dq.y * x3.y + dq.z * x3.z + dq.w * x3.w;         \
    _Pragma("unroll")                                                          \
    for (int off = 32; off >= 1; off >>= 1) {                                  \
        p0 += __shfl_xor(p0, off, 64);                                         \
        p1 += __shfl_xor(p1, off, 64);                                         \
        p2 += __shfl_xor(p2, off, 64);                                         \
        p3 += __shfl_xor(p3, off, 64);                                         \
    }                                                                          \
    const float mn    = fmaxf(fmaxf(fmaxf(p0, p1), fmaxf(p2, p3)), m);         \
    const float scale = __expf(m - mn);                                        \
    const float w0 = __expf(p0 - mn);                                          \
    const float w1 = __expf(p1 - mn);                                          \
    const float w2 = __expf(p2 - mn);                                          \
    const float w3 = __expf(p3 - mn);                                          \
    acc.x = fmaf(w3, x3.x, fmaf(w2, x2.x, fmaf(w1, x1.x, fmaf(w0, x0.x, acc.x * scale)))); \
    acc.y = fmaf(w3, x3.y, fmaf(w2, x2.y, fmaf(w1, x1.y, fmaf(w0, x0.y, acc.y * scale)))); \
    acc.z = fmaf(w3, x3.z, fmaf(w2, x2.z, fmaf(w1, x1.z, fmaf(w0, x0.z, acc.z * scale)))); \
    acc.w = fmaf(w3, x3.w, fmaf(w2, x2.w, fmaf(w1, x1.w, fmaf(w0, x0.w, acc.w * scale)))); \
    l = fmaf(l, scale, w0 + w1 + w2 + w3);                                     \
    m = mn;                                                                    \
} while (0)

// Kernel 1: per-(batch,chunk) partial with online softmax.
// ws layout: acc[B*P][256] floats, then interleaved (m,l)[B*P][2].
__global__ __launch_bounds__(BLOCK) void attn_partial(
    const float* __restrict__ enc,   // [B,T,D]
    const float* __restrict__ dec,   // [B,D]
    float* __restrict__ ws,
    int T, int P, int nblk_total)
{
    const int blk   = blockIdx.x;
    const int b     = blk / P;
    const int chunk = blk % P;
    const int tid   = threadIdx.x;
    const int wave  = tid >> 6;
    const int lane  = tid & 63;

    const int rows_per_block = T / P;
    const int steps = rows_per_block / (WAVES_PER_BLOCK * RBATCH);
    const int step_elems = WAVES_PER_BLOCK * RBATCH * D;

    const float* __restrict__ encb = enc + (size_t)b * T * D;
    const float4 dq = *reinterpret_cast<const float4*>(dec + b * D + lane * 4);

    float  m = -INFINITY;
    float  l = 0.0f;
    float4 acc = {0.0f, 0.0f, 0.0f, 0.0f};

    // step s: wave handles rows chunk*rpb + s*16 + wave*4 .. +3 (block walks
    // one contiguous 16KB stripe per step -- R7's stream consolidation)
    const float* wbase = encb
        + (size_t)(chunk * rows_per_block + wave * RBATCH) * D + lane * 4;

    float4 xa0, xa1, xa2, xa3;
    LOADX(xa0, xa1, xa2, xa3, wbase);

    for (int s = 0; s + 1 < steps; ++s) {
        const float* nb = wbase + (size_t)(s + 1) * step_elems;
        float4 xb0, xb1, xb2, xb3;
        LOADX(xb0, xb1, xb2, xb3, nb);     // next step's 4KB in flight...
        COMPUTE(xa0, xa1, xa2, xa3);        // ...across this whole chain
        xa0 = xb0; xa1 = xb1; xa2 = xb2; xa3 = xb3;
    }
    COMPUTE(xa0, xa1, xa2, xa3);

    // combine the 4 waves' partials in LDS -> one partial per block
    __shared__ float s_acc[WAVES_PER_BLOCK][D];
    __shared__ float s_m[WAVES_PER_BLOCK];
    __shared__ float s_l[WAVES_PER_BLOCK];

    *reinterpret_cast<float4*>(&s_acc[wave][lane * 4]) = acc;
    if (lane == 0) { s_m[wave] = m; s_l[wave] = l; }
    __syncthreads();

    if (wave == 0) {
        const float M = fmaxf(fmaxf(s_m[0], s_m[1]), fmaxf(s_m[2], s_m[3]));
        float4 a = {0.0f, 0.0f, 0.0f, 0.0f};
        float  L = 0.0f;
        #pragma unroll
        for (int wv = 0; wv < WAVES_PER_BLOCK; ++wv) {
            const float e = __expf(s_m[wv] - M);
            const float4 aw = *reinterpret_cast<const float4*>(&s_acc[wv][lane * 4]);
            a.x += e * aw.x; a.y += e * aw.y; a.z += e * aw.z; a.w += e * aw.w;
            L += e * s_l[wv];
        }
        *reinterpret_cast<float4*>(ws + (size_t)blk * D + lane * 4) = a;
        if (lane == 0) {
            float* ml = ws + (size_t)nblk_total * D;
            ml[blk * 2 + 0] = M;
            ml[blk * 2 + 1] = L;
        }
    }
}

// Kernel 2: combine P partials per batch, normalize, write out.
// grid = B*4 blocks; block handles one 64-column quarter;
// 4 wave-slices stride the P loop, LDS reduce.
__global__ __launch_bounds__(BLOCK) void attn_combine(
    const float* __restrict__ ws,
    float* __restrict__ out,
    int P, int nblk_total)
{
    const int b     = blockIdx.x >> 2;
    const int cq    = blockIdx.x & 3;
    const int tid   = threadIdx.x;
    const int lane  = tid & 63;
    const int slice = tid >> 6;
    const int col   = cq * 64 + lane;

    const float* __restrict__ ml = ws + (size_t)nblk_total * D;

    float M = -INFINITY;
    for (int i = 0; i < P; ++i)
        M = fmaxf(M, ml[(b * P + i) * 2 + 0]);

    float a = 0.0f, L = 0.0f;
    for (int i = slice; i < P; i += 4) {
        const int pblk = b * P + i;
        const float e  = __expf(ml[pblk * 2 + 0] - M);
        a = fmaf(e, ws[(size_t)pblk * D + col], a);
        L = fmaf(e, ml[pblk * 2 + 1], L);
    }

    __shared__ float s_a[4][64];
    __shared__ float s_L[4];
    s_a[slice][lane] = a;
    if (lane == 0) s_L[slice] = L;
    __syncthreads();

    if (slice == 0) {
        const float at = s_a[0][lane] + s_a[1][lane] + s_a[2][lane] + s_a[3][lane];
        const float Lt = s_L[0] + s_L[1] + s_L[2] + s_L[3];
        out[b * D + col] = at / Lt;
    }
}

extern "C" void kernel_launch(void* const* d_in, const int* in_sizes, int n_in,
                              void* d_out, int out_size, void* d_ws, size_t ws_size,
                              hipStream_t stream) {
    const float* enc = (const float*)d_in[0];
    const float* dec = (const float*)d_in[1];
    float* out = (float*)d_out;
    float* ws  = (float*)d_ws;

    const int B = in_sizes[1] / D;              // dec is [B, D]
    const int T = in_sizes[0] / in_sizes[1];    // enc is [B, T, D]

    // P chunks per batch; shrink if workspace is small or shape not divisible.
    int P = 64;
    while (P > 1 && ((size_t)B * P * (D + 2) * sizeof(float)) > ws_size) P >>= 1;
    while (P > 1 && (T % (P * WAVES_PER_BLOCK * RBATCH) != 0)) P >>= 1;

    const int nblk = B * P;
    attn_partial<<<nblk, BLOCK, 0, stream>>>(enc, dec, ws, T, P, nblk);
    attn_combine<<<B * 4, BLOCK, 0, stream>>>(ws, out, P, nblk);
}